// Round 7
// baseline (776.914 us; speedup 1.0000x reference)
//
#include <hip/hip_runtime.h>
#include <hip/hip_bf16.h>
#include <math.h>

#define N_SEQ  4096
#define DMODEL 320
#define NHEADS 8
#define DHEAD  40
#define CTXN   77
#define CTXD   768
#define FFI    1280

typedef short s8v __attribute__((ext_vector_type(8)));
typedef short s4v __attribute__((ext_vector_type(4)));
typedef float f4v __attribute__((ext_vector_type(4)));
typedef unsigned short u16;

static __device__ __forceinline__ u16 bf16u(float x) {           // RNE
    unsigned u = __float_as_uint(x);
    return (u16)((u + 0x7FFFu + ((u >> 16) & 1u)) >> 16);
}
static __device__ __forceinline__ float b2f(u16 v) { return __uint_as_float((unsigned)v << 16); }
static __device__ __forceinline__ unsigned pack2(float a, float b) {
    return (unsigned)bf16u(a) | ((unsigned)bf16u(b) << 16);
}

// ---------------- weight pre-convert: dst[o*K+k] = bf16(src) ----------------
struct WC { const float* s; u16* d; int K, O, trans; };
struct WCs { WC a[12]; };
__global__ __launch_bounds__(256) void wcast_k(WCs P) {
    WC w = P.a[blockIdx.y];
    int e = blockIdx.x * 256 + threadIdx.x;
    if (e >= w.K * w.O) return;
    int o = e / w.K, k = e - o * w.K;
    float v = w.trans ? w.s[(size_t)k * w.O + o] : w.s[e];
    w.d[e] = bf16u(v);
}

// ---------------- GroupNorm stats -> per-channel scale/shift ----------------
__global__ __launch_bounds__(256) void gn_stats_k(const float* __restrict__ x,
                                                  const float* __restrict__ gw, const float* __restrict__ gb,
                                                  float* __restrict__ sc, float* __restrict__ sh) {
    __shared__ float red[512];
    __shared__ float ms[2];
    int g = blockIdx.x, t = threadIdx.x;
    const float* xp = x + (size_t)g * 40960;
    float s = 0.f, ss = 0.f;
    for (int i = t; i < 40960; i += 256) { float v = xp[i]; s += v; ss += v * v; }
    red[t] = s; red[256 + t] = ss;
    __syncthreads();
    for (int st = 128; st > 0; st >>= 1) {
        if (t < st) { red[t] += red[t + st]; red[256 + t] += red[256 + t + st]; }
        __syncthreads();
    }
    if (t == 0) {
        float mean = red[0] / 40960.f;
        float var  = red[256] / 40960.f - mean * mean;
        ms[0] = mean; ms[1] = rsqrtf(var + 1e-6f);
    }
    __syncthreads();
    if (t < 10) {
        int c = g * 10 + t;
        float scv = gw[c] * ms[1];
        sc[c] = scv;
        sh[c] = gb[c] - ms[0] * scv;
    }
}

// ---------------- bf16 MFMA GEMM v4: 32x64 tile, 128 threads = 2 waves ----------------
// A modes: 0 bf16 row-major | 1 f32 row-major | 2 f32 col-major w/ GN coef cw[k]*x+cb[k]
//          3 f32 row-major w/ LN from raw sums (lns,lnq) + weights cw/cb
//          4 combine attention K-split partials (Av=Opart bf16, mu=lpart)
// ob_mode: 0 outf row-major f32 | 1 outb row-major bf16 | 2 outb transposed bf16
//          3 outf transposed f32 + res[o][n] (residual)
// lnacc: accumulate per-row sum/sumsq of final values into lns/lnq via atomics.
struct GArg { const u16* Wt; const float* bias; float* outf; u16* outb; int ob_mode; };
#define GP 72
__global__ __launch_bounds__(128) void gemm_v4(const void* __restrict__ Av, int a_mode, int lda,
                                               const float* __restrict__ mu,
                                               const float* __restrict__ cw, const float* __restrict__ cb,
                                               float* __restrict__ lns, float* __restrict__ lnq,
                                               GArg g0, GArg g1, GArg g2,
                                               const float* __restrict__ res,
                                               int Mrows, int K, int Oout, int geglu_off, int obT_stride,
                                               int lnacc) {
    __shared__ __align__(16) u16 As[32 * GP];
    __shared__ __align__(16) u16 Wsm[64 * GP];
    __shared__ __align__(16) u16 Wgm[64 * GP];
    const int t = threadIdx.x;
    const int w = t >> 6, lane = t & 63, c = lane & 15, quad = lane >> 4;
    const int o0 = blockIdx.x * 64, n0 = blockIdx.y * 32;
    GArg g = (blockIdx.z == 0) ? g0 : ((blockIdx.z == 1) ? g1 : g2);
    const bool geglu = (geglu_off > 0);
    const f4v zero = {0.f, 0.f, 0.f, 0.f};
    f4v acc[4]  = {zero, zero, zero, zero};
    f4v accg[4] = {zero, zero, zero, zero};
    const s8v z8 = {0, 0, 0, 0, 0, 0, 0, 0};

    for (int k0 = 0; k0 < K; k0 += 64) {
        __syncthreads();
        if (a_mode == 0) {
            const u16* A = (const u16*)Av;
#pragma unroll
            for (int i = t; i < 256; i += 128) {
                int r = i >> 3, sg = i & 7;
                int n = n0 + r;
                *(s8v*)&As[r * GP + sg * 8] =
                    (n < Mrows) ? *(const s8v*)(A + (size_t)n * lda + k0 + sg * 8) : z8;
            }
        } else if (a_mode == 1) {
            const float* A = (const float*)Av;
            int r = t >> 2, s16 = (t & 3) * 16;
            int n = n0 + r;
            unsigned* dst = (unsigned*)&As[r * GP + s16];
            if (n < Mrows) {
                const float* src = A + (size_t)n * lda + k0 + s16;
#pragma unroll
                for (int i = 0; i < 8; ++i) dst[i] = pack2(src[2 * i], src[2 * i + 1]);
            } else {
#pragma unroll
                for (int i = 0; i < 8; ++i) dst[i] = 0u;
            }
        } else if (a_mode == 2) {       // f32 col-major + GN coef
            const float* A = (const float*)Av;
#pragma unroll
            for (int j = 0; j < 16; ++j) {
                int e = t + 128 * j; int nn = e & 31, kk = e >> 5;
                int n = n0 + nn, kgl = k0 + kk;
                As[nn * GP + kk] = (n < Mrows) ? bf16u(A[(size_t)kgl * lda + n] * cw[kgl] + cb[kgl]) : (u16)0;
            }
        } else if (a_mode == 3) {       // f32 row-major + LN from raw sums
            const float* A = (const float*)Av;
            int r = t >> 2, s16 = (t & 3) * 16;
            int n = n0 + r;
            unsigned* dst = (unsigned*)&As[r * GP + s16];
            if (n < Mrows) {
                float m_ = lns[n] * (1.f / 320.f);
                float var = lnq[n] * (1.f / 320.f) - m_ * m_;
                float rr = rsqrtf(var + 1e-5f);
                const float* src = A + (size_t)n * lda + k0 + s16;
                const float* cwp = cw + k0 + s16;
                const float* cbp = cb + k0 + s16;
#pragma unroll
                for (int i = 0; i < 8; ++i) {
                    float a0 = (src[2 * i]     - m_) * rr * cwp[2 * i]     + cbp[2 * i];
                    float a1 = (src[2 * i + 1] - m_) * rr * cwp[2 * i + 1] + cbp[2 * i + 1];
                    dst[i] = pack2(a0, a1);
                }
            } else {
#pragma unroll
                for (int i = 0; i < 8; ++i) dst[i] = 0u;
            }
        } else {                        // 4: combine attention K-split partials
            const u16* Op = (const u16*)Av;
            const float* lp = mu;
            int r = t >> 2, s16 = (t & 3) * 16;
            int n = n0 + r;
            unsigned* dst = (unsigned*)&As[r * GP + s16];
            int ch0 = k0 + s16;
            int hdA = ch0 / 40;
            int hdB = (ch0 + 15) / 40;
            float invA = 1.f / (lp[(size_t)hdA * N_SEQ + n] + lp[(size_t)(8 + hdA) * N_SEQ + n]);
            float invB = (hdB == hdA) ? invA
                       : 1.f / (lp[(size_t)hdB * N_SEQ + n] + lp[(size_t)(8 + hdB) * N_SEQ + n]);
            float vals[16];
#pragma unroll
            for (int i = 0; i < 16; ++i) {
                int ch = ch0 + i;
                int hd = ch / 40;
                int d  = ch - hd * 40;
                float num = b2f(Op[((size_t)hd * N_SEQ + n) * DHEAD + d])
                          + b2f(Op[((size_t)(8 + hd) * N_SEQ + n) * DHEAD + d]);
                vals[i] = num * ((hd == hdA) ? invA : invB);
            }
#pragma unroll
            for (int i = 0; i < 8; ++i) dst[i] = pack2(vals[2 * i], vals[2 * i + 1]);
        }
#pragma unroll
        for (int i = t; i < 512; i += 128) {
            int oo = i >> 3, sg = i & 7;
            *(s8v*)&Wsm[oo * GP + sg * 8] = *(const s8v*)(g.Wt + (size_t)(o0 + oo) * K + k0 + sg * 8);
        }
        if (geglu) {
#pragma unroll
            for (int i = t; i < 512; i += 128) {
                int oo = i >> 3, sg = i & 7;
                *(s8v*)&Wgm[oo * GP + sg * 8] = *(const s8v*)(g.Wt + (size_t)(o0 + oo + geglu_off) * K + k0 + sg * 8);
            }
        }
        __syncthreads();
        s8v a0 = *(const s8v*)&As[(w * 16 + c) * GP + quad * 8];
        s8v a1 = *(const s8v*)&As[(w * 16 + c) * GP + 32 + quad * 8];
#pragma unroll
        for (int nt = 0; nt < 4; ++nt) {
            s8v b0 = *(const s8v*)&Wsm[(nt * 16 + c) * GP + quad * 8];
            s8v b1 = *(const s8v*)&Wsm[(nt * 16 + c) * GP + 32 + quad * 8];
            acc[nt] = __builtin_amdgcn_mfma_f32_16x16x32_bf16(a0, b0, acc[nt], 0, 0, 0);
            acc[nt] = __builtin_amdgcn_mfma_f32_16x16x32_bf16(a1, b1, acc[nt], 0, 0, 0);
            if (geglu) {
                s8v q0 = *(const s8v*)&Wgm[(nt * 16 + c) * GP + quad * 8];
                s8v q1 = *(const s8v*)&Wgm[(nt * 16 + c) * GP + 32 + quad * 8];
                accg[nt] = __builtin_amdgcn_mfma_f32_16x16x32_bf16(a0, q0, accg[nt], 0, 0, 0);
                accg[nt] = __builtin_amdgcn_mfma_f32_16x16x32_bf16(a1, q1, accg[nt], 0, 0, 0);
            }
        }
    }
    // ---------- epilogue ----------
    float vfin[4][4];
#pragma unroll
    for (int nt = 0; nt < 4; ++nt) {
        int o = o0 + nt * 16 + c;
#pragma unroll
        for (int r = 0; r < 4; ++r) {
            float v = acc[nt][r] + (g.bias ? g.bias[o] : 0.f);
            if (geglu) {
                float gg = accg[nt][r] + g.bias[o + geglu_off];
                v = v * 0.5f * gg * (1.f + erff(gg * 0.70710678118654752f));
            }
            vfin[nt][r] = v;
        }
    }
    if (g.ob_mode == 3) {
#pragma unroll
        for (int nt = 0; nt < 4; ++nt) {
            int o = o0 + nt * 16 + c;
            int nb = n0 + w * 16 + quad * 4;
            const float4 x4 = *(const float4*)(res + (size_t)o * obT_stride + nb);
            float4 o4 = make_float4(vfin[nt][0] + x4.x, vfin[nt][1] + x4.y,
                                    vfin[nt][2] + x4.z, vfin[nt][3] + x4.w);
            *(float4*)(g.outf + (size_t)o * obT_stride + nb) = o4;
        }
        return;
    }
#pragma unroll
    for (int nt = 0; nt < 4; ++nt) {
        int o = o0 + nt * 16 + c;
#pragma unroll
        for (int r = 0; r < 4; ++r) {
            int n = n0 + w * 16 + quad * 4 + r;
            if (n >= Mrows) continue;
            float v = vfin[nt][r];
            if (res) v += res[(size_t)n * Oout + o];
            vfin[nt][r] = v;
            if (g.outf) g.outf[(size_t)n * Oout + o] = v;
            if (g.ob_mode == 1) g.outb[(size_t)n * Oout + o] = bf16u(v);
            else if (g.ob_mode == 2) g.outb[(size_t)o * obT_stride + n] = bf16u(v);
        }
    }
    if (lnacc) {
#pragma unroll
        for (int r = 0; r < 4; ++r) {
            float s = vfin[0][r] + vfin[1][r] + vfin[2][r] + vfin[3][r];
            float q = vfin[0][r] * vfin[0][r] + vfin[1][r] * vfin[1][r]
                    + vfin[2][r] * vfin[2][r] + vfin[3][r] * vfin[3][r];
            s += __shfl_xor(s, 1); s += __shfl_xor(s, 2); s += __shfl_xor(s, 4); s += __shfl_xor(s, 8);
            q += __shfl_xor(q, 1); q += __shfl_xor(q, 2); q += __shfl_xor(q, 4); q += __shfl_xor(q, 8);
            if (c == 0) {
                int n = n0 + w * 16 + quad * 4 + r;
                atomicAdd(&lns[n], s);
                atomicAdd(&lnq[n], q);
            }
        }
    }
}

// ---------------- Self-attention v5: 31KB LDS (Ps overlays Ks), fixed-max softmax, K-split ----------------
// grid (64 qtiles, 8 heads, 2 ksplit), 256 thr = 4 waves; 128-key tiles, 16 tiles/split.
#define KSP 40    // Ks pitch (u16): no dim pad
#define PSP 140   // Ps pitch (u16): conflict-free writes
#define VP  136   // Vs pitch
__global__ __launch_bounds__(256) void attn_self5_k(const u16* __restrict__ qb, const u16* __restrict__ kb,
                                                    const u16* __restrict__ vt,
                                                    u16* __restrict__ Opart, float* __restrict__ lpart) {
    __shared__ __align__(16) u16 KsPs[64 * PSP];   // 8960 u16: Ks (128*40=5120) overlaid by Ps (64*140)
    __shared__ __align__(16) u16 Vs[48 * VP];      // 6528 u16, [dim][key]
    const int t = threadIdx.x;
    const int w = t >> 6, lane = t & 63, c = lane & 15, quad = lane >> 4;
    const int hd = blockIdx.y, ks = blockIdx.z;
    const int q0 = blockIdx.x * 64;
    const float SC2 = 0.15811388300841897f * 1.4426950408889634f;   // scale * log2(e)
    const f4v zero = {0.f, 0.f, 0.f, 0.f};
    const s8v z8 = {0, 0, 0, 0, 0, 0, 0, 0};

    // zero V pad rows 40..47 once
    for (int i = t; i < 8 * VP / 2; i += 256) ((unsigned*)&Vs[40 * VP])[i] = 0u;

    // Q fragments from global (dims 0..31; dims 32..39 on quad 0 only, rest zero-pad)
    const u16* qrow = qb + (size_t)(q0 + w * 16 + c) * DMODEL + hd * DHEAD;
    s8v qa0 = *(const s8v*)(qrow + quad * 8);
    s8v qa1 = z8;
    if (quad == 0) qa1 = *(const s8v*)(qrow + 32);

    float lacc[4] = {0.f, 0.f, 0.f, 0.f};
    f4v o0 = zero, o1 = zero, o2 = zero;

    for (int kt = 0; kt < 16; ++kt) {
        const int k0 = ks * 2048 + kt * 128;
        __syncthreads();   // protect Ks/Vs restage vs prior tile's reads (incl. Ps region)
        for (int i = t; i < 640; i += 256) {           // K: 128 rows x 5 segs (40 dims)
            int r = i / 5, sg = i - r * 5;
            *(s8v*)&KsPs[r * KSP + sg * 8] = *(const s8v*)(kb + (size_t)(k0 + r) * DMODEL + hd * DHEAD + sg * 8);
        }
        for (int i = t; i < 640; i += 256) {           // V^T: 40 dims x 16 segs (128 keys)
            int d = i >> 4, sg = i & 15;
            *(s8v*)&Vs[d * VP + sg * 8] = *(const s8v*)(vt + (size_t)(hd * DHEAD + d) * N_SEQ + k0 + sg * 8);
        }
        __syncthreads();

        // S = Q K^T : 16 q-rows x 128 keys per wave
        f4v sarr[8];
#pragma unroll
        for (int nt = 0; nt < 8; ++nt) {
            const int kr = nt * 16 + c;
            s8v b0 = *(const s8v*)&KsPs[kr * KSP + quad * 8];
            s8v b1 = z8;
            if (quad == 0) b1 = *(const s8v*)&KsPs[kr * KSP + 32];
            f4v s = __builtin_amdgcn_mfma_f32_16x16x32_bf16(qa0, b0, zero, 0, 0, 0);
            s = __builtin_amdgcn_mfma_f32_16x16x32_bf16(qa1, b1, s, 0, 0, 0);
            sarr[nt] = s;
        }
        __syncthreads();   // all Ks reads done before Ps overlay writes

        // fixed-max softmax numerators; Ps overlay at pitch 140 (conflict-free)
        u16* psw = &KsPs[(size_t)(w * 16 + quad * 4) * PSP + c];
#pragma unroll
        for (int reg = 0; reg < 8; ++reg) {
            const int colb = (reg >> 2) * 64 + (reg & 3) * 16;
#pragma unroll
            for (int r = 0; r < 4; ++r) {
                float pv = exp2f(sarr[reg][r] * SC2);
                lacc[r] += pv;
                psw[r * PSP + colb] = (u16)((__float_as_uint(pv) + 0x8000u) >> 16);
            }
        }

        // O += P V (read own wave's Ps rows; b64 pairs for 8B alignment)
        const u16* prow = &KsPs[(size_t)(w * 16 + c) * PSP];
#pragma unroll
        for (int h2 = 0; h2 < 2; ++h2) {
            s8v pa0, pa1;
            {
                s4v lo = *(const s4v*)(prow + h2 * 64 + quad * 8);
                s4v hi = *(const s4v*)(prow + h2 * 64 + quad * 8 + 4);
                pa0 = (s8v){lo[0], lo[1], lo[2], lo[3], hi[0], hi[1], hi[2], hi[3]};
                s4v lo2 = *(const s4v*)(prow + h2 * 64 + 32 + quad * 8);
                s4v hi2 = *(const s4v*)(prow + h2 * 64 + 32 + quad * 8 + 4);
                pa1 = (s8v){lo2[0], lo2[1], lo2[2], lo2[3], hi2[0], hi2[1], hi2[2], hi2[3]};
            }
            {
                s8v v0 = *(const s8v*)&Vs[(0 * 16 + c) * VP + h2 * 64 + quad * 8];
                s8v v1 = *(const s8v*)&Vs[(0 * 16 + c) * VP + h2 * 64 + 32 + quad * 8];
                o0 = __builtin_amdgcn_mfma_f32_16x16x32_bf16(pa0, v0, o0, 0, 0, 0);
                o0 = __builtin_amdgcn_mfma_f32_16x16x32_bf16(pa1, v1, o0, 0, 0, 0);
            }
            {
                s8v v0 = *(const s8v*)&Vs[(1 * 16 + c) * VP + h2 * 64 + quad * 8];
                s8v v1 = *(const s8v*)&Vs[(1 * 16 + c) * VP + h2 * 64 + 32 + quad * 8];
                o1 = __builtin_amdgcn_mfma_f32_16x16x32_bf16(pa0, v0, o1, 0, 0, 0);
                o1 = __builtin_amdgcn_mfma_f32_16x16x32_bf16(pa1, v1, o1, 0, 0, 0);
            }
            {
                s8v v0 = *(const s8v*)&Vs[(2 * 16 + c) * VP + h2 * 64 + quad * 8];
                s8v v1 = *(const s8v*)&Vs[(2 * 16 + c) * VP + h2 * 64 + 32 + quad * 8];
                o2 = __builtin_amdgcn_mfma_f32_16x16x32_bf16(pa0, v0, o2, 0, 0, 0);
                o2 = __builtin_amdgcn_mfma_f32_16x16x32_bf16(pa1, v1, o2, 0, 0, 0);
            }
        }
    }

    const size_t pb = (size_t)(ks * 8 + hd) * N_SEQ;
#pragma unroll
    for (int r = 0; r < 4; ++r) {
        float l = lacc[r];
        l += __shfl_xor(l, 1); l += __shfl_xor(l, 2); l += __shfl_xor(l, 4); l += __shfl_xor(l, 8);
        int q = q0 + w * 16 + quad * 4 + r;
        u16* op = Opart + (pb + q) * DHEAD;
        op[c]      = bf16u(o0[r]);
        op[16 + c] = bf16u(o1[r]);
        if (c < 8) op[32 + c] = bf16u(o2[r]);
        if (c == 0) lpart[pb + q] = l;
    }
}

// ---------------- Cross-attention (M=77): one wave per (row, head) ----------------
__global__ __launch_bounds__(256) void attn_cross2_k(const u16* __restrict__ q, const float* __restrict__ kc,
                                                     const float* __restrict__ vc, u16* __restrict__ out) {
    __shared__ float Pl[4][128];
    const int t = threadIdx.x, w = t >> 6, l = t & 63;
    const int gw = blockIdx.x * 4 + w;
    const int row = gw >> 3, hd = gw & 7;
    const float scale = 0.15811388300841897f;
    float qv[40];
    {
        const u16* qp = q + (size_t)row * DMODEL + hd * DHEAD;
#pragma unroll
        for (int i = 0; i < 5; ++i) {
            s8v v8 = *(const s8v*)(qp + i * 8);
#pragma unroll
            for (int j = 0; j < 8; ++j) qv[i * 8 + j] = b2f((u16)v8[j]) * scale;
        }
    }
    float s1 = -1e30f, s2 = -1e30f;
    if (l < CTXN) {
        const float* kp = kc + (size_t)l * DMODEL + hd * DHEAD;
        float s = 0.f;
#pragma unroll
        for (int i = 0; i < 40; ++i) s += qv[i] * kp[i];
        s1 = s;
    }
    if (l + 64 < CTXN) {
        const float* kp = kc + (size_t)(l + 64) * DMODEL + hd * DHEAD;
        float s = 0.f;
#pragma unroll
        for (int i = 0; i < 40; ++i) s += qv[i] * kp[i];
        s2 = s;
    }
    float mx = fmaxf(s1, s2);
    for (int o = 32; o > 0; o >>= 1) mx = fmaxf(mx, __shfl_xor(mx, o));
    float p1 = (l < CTXN) ? __expf(s1 - mx) : 0.f;
    float p2 = (l + 64 < CTXN) ? __expf(s2 - mx) : 0.f;
    float ps = p1 + p2;
    for (int o = 32; o > 0; o >>= 1) ps += __shfl_xor(ps, o);
    Pl[w][l] = p1;
    Pl[w][l + 64] = p2;
    if (l < DHEAD) {
        float acc = 0.f;
        for (int j = 0; j < CTXN; ++j) acc += Pl[w][j] * vc[(size_t)j * DMODEL + hd * DHEAD + l];
        out[(size_t)row * DMODEL + hd * DHEAD + l] = bf16u(acc / ps);
    }
}

extern "C" void kernel_launch(void* const* d_in, const int* in_sizes, int n_in,
                              void* d_out, int out_size, void* d_ws, size_t ws_size,
                              hipStream_t stream) {
    const float* x      = (const float*)d_in[0];
    const float* ctx    = (const float*)d_in[1];
    const float* gn_w   = (const float*)d_in[2];
    const float* gn_b   = (const float*)d_in[3];
    const float* pin_w  = (const float*)d_in[4];
    const float* pin_b  = (const float*)d_in[5];
    const float* ln1_w  = (const float*)d_in[6];
    const float* ln1_b  = (const float*)d_in[7];
    const float* q1     = (const float*)d_in[8];
    const float* k1     = (const float*)d_in[9];
    const float* v1     = (const float*)d_in[10];
    const float* o1_w   = (const float*)d_in[11];
    const float* o1_b   = (const float*)d_in[12];
    const float* ln2_w  = (const float*)d_in[13];
    const float* ln2_b  = (const float*)d_in[14];
    const float* q2     = (const float*)d_in[15];
    const float* k2     = (const float*)d_in[16];
    const float* v2     = (const float*)d_in[17];
    const float* o2_w   = (const float*)d_in[18];
    const float* o2_b   = (const float*)d_in[19];
    const float* ln3_w  = (const float*)d_in[20];
    const float* ln3_b  = (const float*)d_in[21];
    const float* ff1_w  = (const float*)d_in[22];
    const float* ff1_b  = (const float*)d_in[23];
    const float* ff2_w  = (const float*)d_in[24];
    const float* ff2_b  = (const float*)d_in[25];
    const float* pout_w = (const float*)d_in[26];
    const float* pout_b = (const float*)d_in[27];
    float* out = (float*)d_out;

    char* base = (char*)d_ws;
    float* h     = (float*)(base);                        //  0.00 .. 5.24 MB
    u16*   qb16  = (u16*)(base + 5242880);
    u16*   kb16  = (u16*)(base + 7864320);
    u16*   vt16  = (u16*)(base + 10485760);               // [320][4096]
    u16*   ao16  = (u16*)(base + 13107200);
    u16*   ffg16 = (u16*)(base + 5242880);                // FF alias: qb..ao = [4096][1280]
    u16*   wbase = (u16*)(base + 15728640);
    u16* pinT  = wbase;
    u16* q1T   = pinT  + 102400;
    u16* k1T   = q1T   + 102400;
    u16* v1T   = k1T   + 102400;
    u16* o1T   = v1T   + 102400;
    u16* q2T   = o1T   + 102400;
    u16* o2T   = q2T   + 102400;
    u16* k2T   = o2T   + 102400;
    u16* v2T   = k2T   + 245760;
    u16* ff1T  = v2T   + 245760;
    u16* ff2T  = ff1T  + 819200;
    u16* poutT = ff2T  + 409600;                          // ends at 20,807,680
    float* lnsum = (float*)(base + 20807680);             // 4096
    float* lnss  = lnsum + 4096;                          // 4096  (zeroed together: 32KB)
    float* k2f   = (float*)(base + 20840448);
    float* v2f   = (float*)(base + 20942848);
    u16*   Opart = (u16*)(base + 21045248);               // 2*8*4096*40 bf16 = 5.24 MB
    float* lpart = (float*)(base + 26288128);             // 2*8*4096 f32
    float* gnsc  = (float*)(base + 26550272);             // 320
    float* gnsh  = gnsc + 320;

    // 0. weights -> bf16 [O][K]
    WCs wd;
    wd.a[0]  = {pin_w,  pinT,  320,  320,  0};
    wd.a[1]  = {q1,     q1T,   320,  320,  1};
    wd.a[2]  = {k1,     k1T,   320,  320,  1};
    wd.a[3]  = {v1,     v1T,   320,  320,  1};
    wd.a[4]  = {o1_w,   o1T,   320,  320,  1};
    wd.a[5]  = {q2,     q2T,   320,  320,  1};
    wd.a[6]  = {o2_w,   o2T,   320,  320,  1};
    wd.a[7]  = {k2,     k2T,   768,  320,  1};
    wd.a[8]  = {v2,     v2T,   768,  320,  1};
    wd.a[9]  = {ff1_w,  ff1T,  320,  2560, 1};
    wd.a[10] = {ff2_w,  ff2T,  1280, 320,  1};
    wd.a[11] = {pout_w, poutT, 320,  320,  0};
    wcast_k<<<dim3(3200, 12), 256, 0, stream>>>(wd);

    GArg gz = {nullptr, nullptr, nullptr, nullptr, 0};

    // 1. GN stats; proj_in (GN fused in staging, LN1 sums in epilogue)
    gn_stats_k<<<32, 256, 0, stream>>>(x, gn_w, gn_b, gnsc, gnsh);
    hipMemsetAsync(lnsum, 0, 32768, stream);
    {
        GArg g0 = {pinT, pin_b, h, nullptr, 0};
        gemm_v4<<<dim3(5, 128, 1), 128, 0, stream>>>(x, 2, 4096, nullptr, gnsc, gnsh, lnsum, lnss,
                                                     g0, gz, gz, nullptr, 4096, 320, 320, 0, 0, 1);
    }
    // 2. qkv (LN1 from sums in staging)
    {
        GArg g0 = {q1T, nullptr, nullptr, qb16, 1};
        GArg g1 = {k1T, nullptr, nullptr, kb16, 1};
        GArg g2 = {v1T, nullptr, nullptr, vt16, 2};
        gemm_v4<<<dim3(5, 128, 3), 128, 0, stream>>>(h, 3, 320, nullptr, ln1_w, ln1_b, lnsum, lnss,
                                                     g0, g1, g2, nullptr, 4096, 320, 320, 0, 4096, 0);
    }
    attn_self5_k<<<dim3(64, 8, 2), 256, 0, stream>>>(qb16, kb16, vt16, Opart, lpart);
    // 3. o1 proj (A = combined partials, residual h, LN2 sums)
    hipMemsetAsync(lnsum, 0, 32768, stream);
    {
        GArg g0 = {o1T, o1_b, h, nullptr, 0};
        gemm_v4<<<dim3(5, 128, 1), 128, 0, stream>>>(Opart, 4, 0, lpart, nullptr, nullptr, lnsum, lnss,
                                                     g0, gz, gz, h, 4096, 320, 320, 0, 0, 1);
    }
    // 4. cross-attention block
    {
        GArg g0 = {q2T, nullptr, nullptr, qb16, 1};
        gemm_v4<<<dim3(5, 128, 1), 128, 0, stream>>>(h, 3, 320, nullptr, ln2_w, ln2_b, lnsum, lnss,
                                                     g0, gz, gz, nullptr, 4096, 320, 320, 0, 0, 0);
    }
    {
        GArg g0 = {k2T, nullptr, k2f, nullptr, 0};
        GArg g1 = {v2T, nullptr, v2f, nullptr, 0};
        gemm_v4<<<dim3(5, 3, 2), 128, 0, stream>>>(ctx, 1, 768, nullptr, nullptr, nullptr, nullptr, nullptr,
                                                   g0, g1, gz, nullptr, 77, 768, 320, 0, 0, 0);
    }
    attn_cross2_k<<<8192, 256, 0, stream>>>(qb16, k2f, v2f, ao16);
    hipMemsetAsync(lnsum, 0, 32768, stream);
    {
        GArg g0 = {o2T, o2_b, h, nullptr, 0};
        gemm_v4<<<dim3(5, 128, 1), 128, 0, stream>>>(ao16, 0, 320, nullptr, nullptr, nullptr, lnsum, lnss,
                                                     g0, gz, gz, h, 4096, 320, 320, 0, 0, 1);
    }
    // 5. GEGLU FF (LN3 from sums in ff1 staging)
    {
        GArg g0 = {ff1T, ff1_b, nullptr, ffg16, 1};
        gemm_v4<<<dim3(20, 128, 1), 128, 0, stream>>>(h, 3, 320, nullptr, ln3_w, ln3_b, lnsum, lnss,
                                                      g0, gz, gz, nullptr, 4096, 320, 1280, 1280, 0, 0);
    }
    {
        GArg g0 = {ff2T, ff2_b, h, nullptr, 0};
        gemm_v4<<<dim3(5, 128, 1), 128, 0, stream>>>(ffg16, 0, 1280, nullptr, nullptr, nullptr, nullptr, nullptr,
                                                     g0, gz, gz, h, 4096, 1280, 320, 0, 0, 0);
    }
    // 6. proj_out + input residual (transposed epilogue straight to out)
    {
        GArg g0 = {poutT, pout_b, out, nullptr, 3};
        gemm_v4<<<dim3(5, 128, 1), 128, 0, stream>>>(h, 1, 320, nullptr, nullptr, nullptr, nullptr, nullptr,
                                                     g0, gz, gz, x, 4096, 320, 320, 0, 4096, 0);
    }
}

// Round 8
// 614.513 us; speedup vs baseline: 1.2643x; 1.2643x over previous
//
#include <hip/hip_runtime.h>
#include <hip/hip_bf16.h>
#include <math.h>

#define N_SEQ  4096
#define DMODEL 320
#define NHEADS 8
#define DHEAD  40
#define CTXN   77
#define CTXD   768
#define FFI    1280

typedef short s8v __attribute__((ext_vector_type(8)));
typedef short s4v __attribute__((ext_vector_type(4)));
typedef float f4v __attribute__((ext_vector_type(4)));
typedef unsigned short u16;

static __device__ __forceinline__ u16 bf16u(float x) {           // RNE
    unsigned u = __float_as_uint(x);
    return (u16)((u + 0x7FFFu + ((u >> 16) & 1u)) >> 16);
}
static __device__ __forceinline__ float b2f(u16 v) { return __uint_as_float((unsigned)v << 16); }
static __device__ __forceinline__ unsigned pack2(float a, float b) {
    return (unsigned)bf16u(a) | ((unsigned)bf16u(b) << 16);
}

// ---------------- weight pre-convert: dst[o*K+k] = bf16(src) ----------------
struct WC { const float* s; u16* d; int K, O, trans; };
struct WCs { WC a[12]; };
__global__ __launch_bounds__(256) void wcast_k(WCs P) {
    WC w = P.a[blockIdx.y];
    int e = blockIdx.x * 256 + threadIdx.x;
    if (e >= w.K * w.O) return;
    int o = e / w.K, k = e - o * w.K;
    float v = w.trans ? w.s[(size_t)k * w.O + o] : w.s[e];
    w.d[e] = bf16u(v);
}

// ---------------- GroupNorm stats -> per-channel scale/shift ----------------
__global__ __launch_bounds__(256) void gn_stats_k(const float* __restrict__ x,
                                                  const float* __restrict__ gw, const float* __restrict__ gb,
                                                  float* __restrict__ sc, float* __restrict__ sh) {
    __shared__ float red[512];
    __shared__ float ms[2];
    int g = blockIdx.x, t = threadIdx.x;
    const float* xp = x + (size_t)g * 40960;
    float s = 0.f, ss = 0.f;
    for (int i = t; i < 40960; i += 256) { float v = xp[i]; s += v; ss += v * v; }
    red[t] = s; red[256 + t] = ss;
    __syncthreads();
    for (int st = 128; st > 0; st >>= 1) {
        if (t < st) { red[t] += red[t + st]; red[256 + t] += red[256 + t + st]; }
        __syncthreads();
    }
    if (t == 0) {
        float mean = red[0] / 40960.f;
        float var  = red[256] / 40960.f - mean * mean;
        ms[0] = mean; ms[1] = rsqrtf(var + 1e-6f);
    }
    __syncthreads();
    if (t < 10) {
        int c = g * 10 + t;
        float scv = gw[c] * ms[1];
        sc[c] = scv;
        sh[c] = gb[c] - ms[0] * scv;
    }
}

// ---------------- LayerNorm stats (mu, 1/sigma per row) ----------------
__global__ __launch_bounds__(256) void ln_stats_k(const float* __restrict__ in,
                                                  float* __restrict__ mu, float* __restrict__ rs) {
    int row = blockIdx.x * 4 + (threadIdx.x >> 6), l = threadIdx.x & 63;
    const float* p = in + (size_t)row * DMODEL;
    float s = 0.f, ss = 0.f;
#pragma unroll
    for (int j = 0; j < 5; ++j) { float v = p[l + 64 * j]; s += v; ss += v * v; }
    for (int o = 32; o > 0; o >>= 1) { s += __shfl_xor(s, o); ss += __shfl_xor(ss, o); }
    if (l == 0) {
        float mean = s * (1.f / 320.f);
        float var  = ss * (1.f / 320.f) - mean * mean;
        mu[row] = mean;
        rs[row] = rsqrtf(var + 1e-5f);
    }
}

// ---------------- bf16 MFMA GEMM (64x64 tile, 256 thr = 4 waves) ----------------
// A modes: 0 bf16 row-major | 1 f32 row-major | 2 f32 col-major w/ GN coef cw[k]*x+cb[k]
//          3 f32 row-major w/ LN (mu/rs arrays) + weights cw/cb
// ob_mode: 0 outf row-major f32 | 1 outb row-major bf16 | 2 outb transposed bf16
//          3 outf transposed f32 + res[o][n] | 4 qkv split (g0/g1/g2.outb = q,k row-major; v transposed)
struct GArg { const u16* Wt; const float* bias; float* outf; u16* outb; int ob_mode; };
#define GP 72
__global__ __launch_bounds__(256) void gemm_v3(const void* __restrict__ Av, int a_mode, int lda,
                                               const float* __restrict__ mu, const float* __restrict__ rs,
                                               const float* __restrict__ cw, const float* __restrict__ cb,
                                               GArg g0, GArg g1, GArg g2,
                                               const float* __restrict__ res,
                                               int Mrows, int K, int Oout, int geglu_off, int obT_stride) {
    __shared__ __align__(16) u16 As[64 * GP];
    __shared__ __align__(16) u16 Wsm[64 * GP];
    __shared__ __align__(16) u16 Wgm[64 * GP];
    const int t = threadIdx.x;
    const int w = t >> 6, lane = t & 63, c = lane & 15, quad = lane >> 4;
    const int o0 = blockIdx.x * 64, n0 = blockIdx.y * 64;
    GArg g = (blockIdx.z == 0) ? g0 : ((blockIdx.z == 1) ? g1 : g2);
    const bool geglu = (geglu_off > 0);
    const f4v zero = {0.f, 0.f, 0.f, 0.f};
    f4v acc[4]  = {zero, zero, zero, zero};
    f4v accg[4] = {zero, zero, zero, zero};
    const s8v z8 = {0, 0, 0, 0, 0, 0, 0, 0};

    for (int k0 = 0; k0 < K; k0 += 64) {
        __syncthreads();
        if (a_mode == 0) {
            const u16* A = (const u16*)Av;
#pragma unroll
            for (int i = t; i < 512; i += 256) {
                int r = i >> 3, sg = i & 7;
                int n = n0 + r;
                *(s8v*)&As[r * GP + sg * 8] =
                    (n < Mrows) ? *(const s8v*)(A + (size_t)n * lda + k0 + sg * 8) : z8;
            }
        } else if (a_mode == 1) {
            const float* A = (const float*)Av;
            int r = t >> 2, s16 = (t & 3) * 16;
            int n = n0 + r;
            unsigned* dst = (unsigned*)&As[r * GP + s16];
            if (n < Mrows) {
                const float* src = A + (size_t)n * lda + k0 + s16;
#pragma unroll
                for (int i = 0; i < 8; ++i) dst[i] = pack2(src[2 * i], src[2 * i + 1]);
            } else {
#pragma unroll
                for (int i = 0; i < 8; ++i) dst[i] = 0u;
            }
        } else if (a_mode == 2) {
            const float* A = (const float*)Av;
#pragma unroll
            for (int j = 0; j < 16; ++j) {
                int e = t + 256 * j; int nn = e & 63, kk = e >> 6;
                int n = n0 + nn, kgl = k0 + kk;
                As[nn * GP + kk] = (n < Mrows) ? bf16u(A[(size_t)kgl * lda + n] * cw[kgl] + cb[kgl]) : (u16)0;
            }
        } else {   // 3: LN-fused f32 row-major
            const float* A = (const float*)Av;
            int r = t >> 2, s16 = (t & 3) * 16;
            int n = n0 + r;
            unsigned* dst = (unsigned*)&As[r * GP + s16];
            if (n < Mrows) {
                const float* src = A + (size_t)n * lda + k0 + s16;
                const float* cwp = cw + k0 + s16;
                const float* cbp = cb + k0 + s16;
                float m_ = mu[n], rr = rs[n];
#pragma unroll
                for (int i = 0; i < 8; ++i) {
                    float a0 = (src[2 * i]     - m_) * rr * cwp[2 * i]     + cbp[2 * i];
                    float a1 = (src[2 * i + 1] - m_) * rr * cwp[2 * i + 1] + cbp[2 * i + 1];
                    dst[i] = pack2(a0, a1);
                }
            } else {
#pragma unroll
                for (int i = 0; i < 8; ++i) dst[i] = 0u;
            }
        }
#pragma unroll
        for (int i = t; i < 512; i += 256) {
            int oo = i >> 3, sg = i & 7;
            *(s8v*)&Wsm[oo * GP + sg * 8] = *(const s8v*)(g.Wt + (size_t)(o0 + oo) * K + k0 + sg * 8);
        }
        if (geglu) {
#pragma unroll
            for (int i = t; i < 512; i += 256) {
                int oo = i >> 3, sg = i & 7;
                *(s8v*)&Wgm[oo * GP + sg * 8] = *(const s8v*)(g.Wt + (size_t)(o0 + oo + geglu_off) * K + k0 + sg * 8);
            }
        }
        __syncthreads();
        s8v a0 = *(const s8v*)&As[(w * 16 + c) * GP + quad * 8];
        s8v a1 = *(const s8v*)&As[(w * 16 + c) * GP + 32 + quad * 8];
#pragma unroll
        for (int nt = 0; nt < 4; ++nt) {
            s8v b0 = *(const s8v*)&Wsm[(nt * 16 + c) * GP + quad * 8];
            s8v b1 = *(const s8v*)&Wsm[(nt * 16 + c) * GP + 32 + quad * 8];
            acc[nt] = __builtin_amdgcn_mfma_f32_16x16x32_bf16(a0, b0, acc[nt], 0, 0, 0);
            acc[nt] = __builtin_amdgcn_mfma_f32_16x16x32_bf16(a1, b1, acc[nt], 0, 0, 0);
            if (geglu) {
                s8v q0 = *(const s8v*)&Wgm[(nt * 16 + c) * GP + quad * 8];
                s8v q1 = *(const s8v*)&Wgm[(nt * 16 + c) * GP + 32 + quad * 8];
                accg[nt] = __builtin_amdgcn_mfma_f32_16x16x32_bf16(a0, q0, accg[nt], 0, 0, 0);
                accg[nt] = __builtin_amdgcn_mfma_f32_16x16x32_bf16(a1, q1, accg[nt], 0, 0, 0);
            }
        }
    }
#pragma unroll
    for (int nt = 0; nt < 4; ++nt) {
        int o = o0 + nt * 16 + c;
        float vv[4];
#pragma unroll
        for (int r = 0; r < 4; ++r) {
            float v = acc[nt][r] + (g.bias ? g.bias[o] : 0.f);
            if (geglu) {
                float gg = accg[nt][r] + g.bias[o + geglu_off];
                v = v * 0.5f * gg * (1.f + erff(gg * 0.70710678118654752f));
            }
            vv[r] = v;
        }
        if (g.ob_mode == 3) {
            int nb = n0 + w * 16 + quad * 4;
            const float4 x4 = *(const float4*)(res + (size_t)o * obT_stride + nb);
            float4 o4 = make_float4(vv[0] + x4.x, vv[1] + x4.y, vv[2] + x4.z, vv[3] + x4.w);
            *(float4*)(g.outf + (size_t)o * obT_stride + nb) = o4;
        } else if (g.ob_mode == 4) {
#pragma unroll
            for (int r = 0; r < 4; ++r) {
                int n = n0 + w * 16 + quad * 4 + r;
                u16 bv = bf16u(vv[r]);
                if (o < 320)      g0.outb[(size_t)n * 320 + o] = bv;
                else if (o < 640) g1.outb[(size_t)n * 320 + (o - 320)] = bv;
                else              g2.outb[(size_t)(o - 640) * obT_stride + n] = bv;
            }
        } else {
#pragma unroll
            for (int r = 0; r < 4; ++r) {
                int n = n0 + w * 16 + quad * 4 + r;
                if (n >= Mrows) continue;
                float v = vv[r];
                if (res) v += res[(size_t)n * Oout + o];
                if (g.outf) g.outf[(size_t)n * Oout + o] = v;
                if (g.ob_mode == 1) g.outb[(size_t)n * Oout + o] = bf16u(v);
                else if (g.ob_mode == 2) g.outb[(size_t)o * obT_stride + n] = bf16u(v);
            }
        }
    }
}

// ---------------- Self-attention v5: 31KB LDS (Ps overlays Ks), fixed-max softmax, K-split ----------------
#define KSP 40    // Ks pitch (u16)
#define PSP 140   // Ps pitch (u16), conflict-free writes
#define VP  136   // Vs pitch
__global__ __launch_bounds__(256) void attn_self5_k(const u16* __restrict__ qb, const u16* __restrict__ kb,
                                                    const u16* __restrict__ vt,
                                                    u16* __restrict__ Opart, float* __restrict__ lpart) {
    __shared__ __align__(16) u16 KsPs[64 * PSP];   // Ks (128*40) overlaid by Ps (64*140)
    __shared__ __align__(16) u16 Vs[48 * VP];
    const int t = threadIdx.x;
    const int w = t >> 6, lane = t & 63, c = lane & 15, quad = lane >> 4;
    const int hd = blockIdx.y, ks = blockIdx.z;
    const int q0 = blockIdx.x * 64;
    const float SC2 = 0.15811388300841897f * 1.4426950408889634f;
    const f4v zero = {0.f, 0.f, 0.f, 0.f};
    const s8v z8 = {0, 0, 0, 0, 0, 0, 0, 0};

    for (int i = t; i < 8 * VP / 2; i += 256) ((unsigned*)&Vs[40 * VP])[i] = 0u;

    const u16* qrow = qb + (size_t)(q0 + w * 16 + c) * DMODEL + hd * DHEAD;
    s8v qa0 = *(const s8v*)(qrow + quad * 8);
    s8v qa1 = z8;
    if (quad == 0) qa1 = *(const s8v*)(qrow + 32);

    float lacc[4] = {0.f, 0.f, 0.f, 0.f};
    f4v o0 = zero, o1 = zero, o2 = zero;

    for (int kt = 0; kt < 16; ++kt) {
        const int k0 = ks * 2048 + kt * 128;
        __syncthreads();
        for (int i = t; i < 640; i += 256) {
            int r = i / 5, sg = i - r * 5;
            *(s8v*)&KsPs[r * KSP + sg * 8] = *(const s8v*)(kb + (size_t)(k0 + r) * DMODEL + hd * DHEAD + sg * 8);
        }
        for (int i = t; i < 640; i += 256) {
            int d = i >> 4, sg = i & 15;
            *(s8v*)&Vs[d * VP + sg * 8] = *(const s8v*)(vt + (size_t)(hd * DHEAD + d) * N_SEQ + k0 + sg * 8);
        }
        __syncthreads();

        f4v sarr[8];
#pragma unroll
        for (int nt = 0; nt < 8; ++nt) {
            const int kr = nt * 16 + c;
            s8v b0 = *(const s8v*)&KsPs[kr * KSP + quad * 8];
            s8v b1 = z8;
            if (quad == 0) b1 = *(const s8v*)&KsPs[kr * KSP + 32];
            f4v s = __builtin_amdgcn_mfma_f32_16x16x32_bf16(qa0, b0, zero, 0, 0, 0);
            s = __builtin_amdgcn_mfma_f32_16x16x32_bf16(qa1, b1, s, 0, 0, 0);
            sarr[nt] = s;
        }
        __syncthreads();

        u16* psw = &KsPs[(size_t)(w * 16 + quad * 4) * PSP + c];
#pragma unroll
        for (int reg = 0; reg < 8; ++reg) {
            const int colb = (reg >> 2) * 64 + (reg & 3) * 16;
#pragma unroll
            for (int r = 0; r < 4; ++r) {
                float pv = exp2f(sarr[reg][r] * SC2);
                lacc[r] += pv;
                psw[r * PSP + colb] = (u16)((__float_as_uint(pv) + 0x8000u) >> 16);
            }
        }

        const u16* prow = &KsPs[(size_t)(w * 16 + c) * PSP];
#pragma unroll
        for (int h2 = 0; h2 < 2; ++h2) {
            s8v pa0, pa1;
            {
                s4v lo = *(const s4v*)(prow + h2 * 64 + quad * 8);
                s4v hi = *(const s4v*)(prow + h2 * 64 + quad * 8 + 4);
                pa0 = (s8v){lo[0], lo[1], lo[2], lo[3], hi[0], hi[1], hi[2], hi[3]};
                s4v lo2 = *(const s4v*)(prow + h2 * 64 + 32 + quad * 8);
                s4v hi2 = *(const s4v*)(prow + h2 * 64 + 32 + quad * 8 + 4);
                pa1 = (s8v){lo2[0], lo2[1], lo2[2], lo2[3], hi2[0], hi2[1], hi2[2], hi2[3]};
            }
            {
                s8v v0 = *(const s8v*)&Vs[(0 * 16 + c) * VP + h2 * 64 + quad * 8];
                s8v v1 = *(const s8v*)&Vs[(0 * 16 + c) * VP + h2 * 64 + 32 + quad * 8];
                o0 = __builtin_amdgcn_mfma_f32_16x16x32_bf16(pa0, v0, o0, 0, 0, 0);
                o0 = __builtin_amdgcn_mfma_f32_16x16x32_bf16(pa1, v1, o0, 0, 0, 0);
            }
            {
                s8v v0 = *(const s8v*)&Vs[(1 * 16 + c) * VP + h2 * 64 + quad * 8];
                s8v v1 = *(const s8v*)&Vs[(1 * 16 + c) * VP + h2 * 64 + 32 + quad * 8];
                o1 = __builtin_amdgcn_mfma_f32_16x16x32_bf16(pa0, v0, o1, 0, 0, 0);
                o1 = __builtin_amdgcn_mfma_f32_16x16x32_bf16(pa1, v1, o1, 0, 0, 0);
            }
            {
                s8v v0 = *(const s8v*)&Vs[(2 * 16 + c) * VP + h2 * 64 + quad * 8];
                s8v v1 = *(const s8v*)&Vs[(2 * 16 + c) * VP + h2 * 64 + 32 + quad * 8];
                o2 = __builtin_amdgcn_mfma_f32_16x16x32_bf16(pa0, v0, o2, 0, 0, 0);
                o2 = __builtin_amdgcn_mfma_f32_16x16x32_bf16(pa1, v1, o2, 0, 0, 0);
            }
        }
    }

    const size_t pb = (size_t)(ks * 8 + hd) * N_SEQ;
#pragma unroll
    for (int r = 0; r < 4; ++r) {
        float l = lacc[r];
        l += __shfl_xor(l, 1); l += __shfl_xor(l, 2); l += __shfl_xor(l, 4); l += __shfl_xor(l, 8);
        int q = q0 + w * 16 + quad * 4 + r;
        u16* op = Opart + (pb + q) * DHEAD;
        op[c]      = bf16u(o0[r]);
        op[16 + c] = bf16u(o1[r]);
        if (c < 8) op[32 + c] = bf16u(o2[r]);
        if (c == 0) lpart[pb + q] = l;
    }
}

// ---------------- attention combine: ao[n][c] = (O0+O1)/(l0+l1) ----------------
__global__ __launch_bounds__(256) void attn_comb_k(const u16* __restrict__ Opart, const float* __restrict__ lpart,
                                                   u16* __restrict__ ao) {
    int idx = blockIdx.x * 256 + threadIdx.x;
    int n = idx / DMODEL, c = idx - n * DMODEL;
    int hd = c / DHEAD, d = c - hd * DHEAD;
    size_t b0 = ((size_t)hd * N_SEQ + n) * DHEAD + d;
    size_t b1 = ((size_t)(8 + hd) * N_SEQ + n) * DHEAD + d;
    float num = b2f(Opart[b0]) + b2f(Opart[b1]);
    float den = lpart[(size_t)hd * N_SEQ + n] + lpart[(size_t)(8 + hd) * N_SEQ + n];
    ao[idx] = bf16u(num / den);
}

// ---------------- Cross-attention (M=77): one wave per (row, head) ----------------
__global__ __launch_bounds__(256) void attn_cross2_k(const u16* __restrict__ q, const float* __restrict__ kc,
                                                     const float* __restrict__ vc, u16* __restrict__ out) {
    __shared__ float Pl[4][128];
    const int t = threadIdx.x, w = t >> 6, l = t & 63;
    const int gw = blockIdx.x * 4 + w;
    const int row = gw >> 3, hd = gw & 7;
    const float scale = 0.15811388300841897f;
    float qv[40];
    {
        const u16* qp = q + (size_t)row * DMODEL + hd * DHEAD;
#pragma unroll
        for (int i = 0; i < 5; ++i) {
            s8v v8 = *(const s8v*)(qp + i * 8);
#pragma unroll
            for (int j = 0; j < 8; ++j) qv[i * 8 + j] = b2f((u16)v8[j]) * scale;
        }
    }
    float s1 = -1e30f, s2 = -1e30f;
    if (l < CTXN) {
        const float* kp = kc + (size_t)l * DMODEL + hd * DHEAD;
        float s = 0.f;
#pragma unroll
        for (int i = 0; i < 40; ++i) s += qv[i] * kp[i];
        s1 = s;
    }
    if (l + 64 < CTXN) {
        const float* kp = kc + (size_t)(l + 64) * DMODEL + hd * DHEAD;
        float s = 0.f;
#pragma unroll
        for (int i = 0; i < 40; ++i) s += qv[i] * kp[i];
        s2 = s;
    }
    float mx = fmaxf(s1, s2);
    for (int o = 32; o > 0; o >>= 1) mx = fmaxf(mx, __shfl_xor(mx, o));
    float p1 = (l < CTXN) ? __expf(s1 - mx) : 0.f;
    float p2 = (l + 64 < CTXN) ? __expf(s2 - mx) : 0.f;
    float ps = p1 + p2;
    for (int o = 32; o > 0; o >>= 1) ps += __shfl_xor(ps, o);
    Pl[w][l] = p1;
    Pl[w][l + 64] = p2;
    if (l < DHEAD) {
        float acc = 0.f;
        for (int j = 0; j < CTXN; ++j) acc += Pl[w][j] * vc[(size_t)j * DMODEL + hd * DHEAD + l];
        out[(size_t)row * DMODEL + hd * DHEAD + l] = bf16u(acc / ps);
    }
}

extern "C" void kernel_launch(void* const* d_in, const int* in_sizes, int n_in,
                              void* d_out, int out_size, void* d_ws, size_t ws_size,
                              hipStream_t stream) {
    const float* x      = (const float*)d_in[0];
    const float* ctx    = (const float*)d_in[1];
    const float* gn_w   = (const float*)d_in[2];
    const float* gn_b   = (const float*)d_in[3];
    const float* pin_w  = (const float*)d_in[4];
    const float* pin_b  = (const float*)d_in[5];
    const float* ln1_w  = (const float*)d_in[6];
    const float* ln1_b  = (const float*)d_in[7];
    const float* q1     = (const float*)d_in[8];
    const float* k1     = (const float*)d_in[9];
    const float* v1     = (const float*)d_in[10];
    const float* o1_w   = (const float*)d_in[11];
    const float* o1_b   = (const float*)d_in[12];
    const float* ln2_w  = (const float*)d_in[13];
    const float* ln2_b  = (const float*)d_in[14];
    const float* q2     = (const float*)d_in[15];
    const float* k2     = (const float*)d_in[16];
    const float* v2     = (const float*)d_in[17];
    const float* o2_w   = (const float*)d_in[18];
    const float* o2_b   = (const float*)d_in[19];
    const float* ln3_w  = (const float*)d_in[20];
    const float* ln3_b  = (const float*)d_in[21];
    const float* ff1_w  = (const float*)d_in[22];
    const float* ff1_b  = (const float*)d_in[23];
    const float* ff2_w  = (const float*)d_in[24];
    const float* ff2_b  = (const float*)d_in[25];
    const float* pout_w = (const float*)d_in[26];
    const float* pout_b = (const float*)d_in[27];
    float* out = (float*)d_out;

    char* base = (char*)d_ws;
    float* h     = (float*)(base);                        //  0 .. 5.24 MB
    u16*   qb16  = (u16*)(base + 5242880);
    u16*   kb16  = (u16*)(base + 7864320);
    u16*   vt16  = (u16*)(base + 10485760);               // [320][4096]
    u16*   ao16  = (u16*)(base + 13107200);
    u16*   ffg16 = (u16*)(base + 5242880);                // FF alias
    u16*   wbase = (u16*)(base + 15728640);
    u16* pinT  = wbase;
    u16* q1T   = pinT  + 102400;     // q1T/k1T/v1T contiguous => qkv concat [960][320]
    u16* k1T   = q1T   + 102400;
    u16* v1T   = k1T   + 102400;
    u16* o1T   = v1T   + 102400;
    u16* q2T   = o1T   + 102400;
    u16* o2T   = q2T   + 102400;
    u16* k2T   = o2T   + 102400;
    u16* v2T   = k2T   + 245760;
    u16* ff1T  = v2T   + 245760;
    u16* ff2T  = ff1T  + 819200;
    u16* poutT = ff2T  + 409600;                          // ends 20,807,680
    float* lnmu = (float*)(base + 20807680);              // 4096
    float* lnrs = lnmu + 4096;
    float* k2f  = lnrs + 4096;                            // 77*320 pad 25600
    float* v2f  = k2f + 25600;
    u16*   Opart = (u16*)(v2f + 25600);                   // 2*8*4096*40 bf16
    float* lpart = (float*)(Opart + 2 * 8 * 4096 * 40);   // 2*8*4096 f32
    float* gnsc  = lpart + 2 * 8 * 4096;                  // 320
    float* gnsh  = gnsc + 320;

    // 0. weights -> bf16 [O][K]
    WCs wd;
    wd.a[0]  = {pin_w,  pinT,  320,  320,  0};
    wd.a[1]  = {q1,     q1T,   320,  320,  1};
    wd.a[2]  = {k1,     k1T,   320,  320,  1};
    wd.a[3]  = {v1,     v1T,   320,  320,  1};
    wd.a[4]  = {o1_w,   o1T,   320,  320,  1};
    wd.a[5]  = {q2,     q2T,   320,  320,  1};
    wd.a[6]  = {o2_w,   o2T,   320,  320,  1};
    wd.a[7]  = {k2,     k2T,   768,  320,  1};
    wd.a[8]  = {v2,     v2T,   768,  320,  1};
    wd.a[9]  = {ff1_w,  ff1T,  320,  2560, 1};
    wd.a[10] = {ff2_w,  ff2T,  1280, 320,  1};
    wd.a[11] = {pout_w, poutT, 320,  320,  0};
    wcast_k<<<dim3(3200, 12), 256, 0, stream>>>(wd);

    GArg gz = {nullptr, nullptr, nullptr, nullptr, 0};

    // 1. GN stats; proj_in (GN fused in staging)
    gn_stats_k<<<32, 256, 0, stream>>>(x, gn_w, gn_b, gnsc, gnsh);
    {
        GArg g0 = {pinT, pin_b, h, nullptr, 0};
        gemm_v3<<<dim3(5, 64, 1), 256, 0, stream>>>(x, 2, 4096, nullptr, nullptr, gnsc, gnsh,
                                                    g0, gz, gz, nullptr, 4096, 320, 320, 0, 0);
    }
    // 2. qkv fused 960-out GEMM (LN1 in staging)
    ln_stats_k<<<1024, 256, 0, stream>>>(h, lnmu, lnrs);
    {
        GArg g0 = {q1T, nullptr, nullptr, qb16, 4};
        GArg g1 = {nullptr, nullptr, nullptr, kb16, 0};
        GArg g2 = {nullptr, nullptr, nullptr, vt16, 0};
        gemm_v3<<<dim3(15, 64, 1), 256, 0, stream>>>(h, 3, 320, lnmu, lnrs, ln1_w, ln1_b,
                                                     g0, g1, g2, nullptr, 4096, 320, 960, 0, 4096);
    }
    attn_self5_k<<<dim3(64, 8, 2), 256, 0, stream>>>(qb16, kb16, vt16, Opart, lpart);
    attn_comb_k<<<5120, 256, 0, stream>>>(Opart, lpart, ao16);
    {
        GArg g0 = {o1T, o1_b, h, nullptr, 0};
        gemm_v3<<<dim3(5, 64, 1), 256, 0, stream>>>(ao16, 0, 320, nullptr, nullptr, nullptr, nullptr,
                                                    g0, gz, gz, h, 4096, 320, 320, 0, 0);
    }
    // 3. cross-attention block (LN2 in q2 staging)
    ln_stats_k<<<1024, 256, 0, stream>>>(h, lnmu, lnrs);
    {
        GArg g0 = {q2T, nullptr, nullptr, qb16, 1};
        gemm_v3<<<dim3(5, 64, 1), 256, 0, stream>>>(h, 3, 320, lnmu, lnrs, ln2_w, ln2_b,
                                                    g0, gz, gz, nullptr, 4096, 320, 320, 0, 0);
    }
    {
        GArg g0 = {k2T, nullptr, k2f, nullptr, 0};
        GArg g1 = {v2T, nullptr, v2f, nullptr, 0};
        gemm_v3<<<dim3(5, 2, 2), 256, 0, stream>>>(ctx, 1, 768, nullptr, nullptr, nullptr, nullptr,
                                                   g0, g1, gz, nullptr, 77, 768, 320, 0, 0);
    }
    attn_cross2_k<<<8192, 256, 0, stream>>>(qb16, k2f, v2f, ao16);
    {
        GArg g0 = {o2T, o2_b, h, nullptr, 0};
        gemm_v3<<<dim3(5, 64, 1), 256, 0, stream>>>(ao16, 0, 320, nullptr, nullptr, nullptr, nullptr,
                                                    g0, gz, gz, h, 4096, 320, 320, 0, 0);
    }
    // 4. GEGLU FF (LN3 in ff1 staging)
    ln_stats_k<<<1024, 256, 0, stream>>>(h, lnmu, lnrs);
    {
        GArg g0 = {ff1T, ff1_b, nullptr, ffg16, 1};
        gemm_v3<<<dim3(20, 64, 1), 256, 0, stream>>>(h, 3, 320, lnmu, lnrs, ln3_w, ln3_b,
                                                     g0, gz, gz, nullptr, 4096, 320, 1280, 1280, 0);
    }
    {
        GArg g0 = {ff2T, ff2_b, h, nullptr, 0};
        gemm_v3<<<dim3(5, 64, 1), 256, 0, stream>>>(ffg16, 0, 1280, nullptr, nullptr, nullptr, nullptr,
                                                    g0, gz, gz, h, 4096, 1280, 320, 0, 0);
    }
    // 5. proj_out + input residual (transposed epilogue to out)
    {
        GArg g0 = {poutT, pout_b, out, nullptr, 3};
        gemm_v3<<<dim3(5, 64, 1), 256, 0, stream>>>(h, 1, 320, nullptr, nullptr, nullptr, nullptr,
                                                    g0, gz, gz, x, 4096, 320, 320, 0, 4096);
    }
}